// Round 2
// baseline (705.403 us; speedup 1.0000x reference)
//
#include <hip/hip_runtime.h>

#define N_PTS   20000
#define M_ATOMS 10000
#define DAT     64
#define HID     129
#define KNN     16
#define NLAYERS 3

#define TILE_ATOMS 2048
#define NTILES     5          // 5*2048 = 10240 >= 10000
#define M_PAD      10240
#define A_STRIDE   132        // padded row stride for A (16B aligned rows)
#define PTS_PER_WAVE  4
#define PTS_PER_BLOCK 16      // 4 waves * 4

// ---------------- pack y -> float4(x,y,z,|y|^2), INF-padded ----------------
__global__ void pack_y_kernel(const float* __restrict__ y, float4* __restrict__ yp) {
    int i = blockIdx.x * blockDim.x + threadIdx.x;
    if (i >= M_PAD) return;
    if (i < M_ATOMS) {
        float a = y[3*i], b = y[3*i+1], c = y[3*i+2];
        float s = (a*a + b*b) + c*c;          // same order as (y**2).sum(1)
        yp[i] = make_float4(a, b, c, s);
    } else {
        yp[i] = make_float4(0.f, 0.f, 0.f, __builtin_inff());  // pad -> d2=INF
    }
}

// ---------------- brute-force exact kNN (K=16) ----------------
// One wave handles 4 points; tile element loaded ONCE per wave and evaluated
// against all 4 points (coords pre-broadcast to registers). Top-16 list held
// distributed in lanes 0..15 (sorted ascending); insert = ballot + shfl shift.
__global__ __launch_bounds__(256) void knn_kernel(
        const float* __restrict__ x, const float4* __restrict__ yp,
        int* __restrict__ oidx, float* __restrict__ odist) {
    __shared__ float4 tile[TILE_ATOMS];     // 32 KiB
    const int tid  = threadIdx.x;
    const int lane = tid & 63;
    const int wid  = tid >> 6;
    const int base_pt = blockIdx.x * PTS_PER_BLOCK + wid * PTS_PER_WAVE;
    const float INF = __builtin_inff();

    // lanes 0..3 hold coords of this wave's 4 points
    float rx0 = 0.f, rx1 = 0.f, rx2 = 0.f, rx3 = 0.f;
    if (lane < PTS_PER_WAVE) {
        int pt = base_pt + lane;
        if (pt < N_PTS) {
            rx0 = x[3*pt]; rx1 = x[3*pt+1]; rx2 = x[3*pt+2];
            rx3 = (rx0*rx0 + rx1*rx1) + rx2*rx2;   // (x**2).sum(1) order
        }
    }
    // pre-broadcast to all lanes (removes shfls from the hot loop)
    float px[PTS_PER_WAVE], py[PTS_PER_WAVE], pz[PTS_PER_WAVE], ps[PTS_PER_WAVE];
#pragma unroll
    for (int p = 0; p < PTS_PER_WAVE; ++p) {
        px[p] = __shfl(rx0, p); py[p] = __shfl(rx1, p);
        pz[p] = __shfl(rx2, p); ps[p] = __shfl(rx3, p);
    }

    float Ld[PTS_PER_WAVE];  int Li[PTS_PER_WAVE];  float kth[PTS_PER_WAVE];
#pragma unroll
    for (int p = 0; p < PTS_PER_WAVE; ++p) { Ld[p] = INF; Li[p] = 0; kth[p] = INF; }

    for (int t = 0; t < NTILES; ++t) {
        __syncthreads();
        for (int j = tid; j < TILE_ATOMS; j += 256) tile[j] = yp[t * TILE_ATOMS + j];
        __syncthreads();
        const int abase = t * TILE_ATOMS;
#pragma unroll 2
        for (int it = 0; it < TILE_ATOMS / 64; ++it) {
            float4 a = tile[it * 64 + lane];        // read ONCE, serve 4 points
            const int cbase = abase + it * 64;
#pragma unroll
            for (int p = 0; p < PTS_PER_WAVE; ++p) {
                // selection metric in the SAME algebra as reference: (x2 - 2*dot) + y2
                float dot = (px[p] * a.x + py[p] * a.y) + pz[p] * a.z;
                float d2  = (ps[p] - 2.f * dot) + a.w;
                unsigned long long mask = __ballot(d2 < kth[p]);
                while (mask) {                      // uniform loop
                    int src = __builtin_ctzll(mask);  // ascending atom index
                    mask &= mask - 1;
                    float v = __shfl(d2, src);
                    if (v < kth[p]) {               // recheck vs updated kth
                        int mi = cbase + src;
                        bool cond = Ld[p] > v;      // strict: stable ties (lower idx first)
                        unsigned long long bal = __ballot(cond);
                        float pd = __shfl_up(Ld[p], 1);
                        int   pi = __shfl_up(Li[p], 1);
                        bool cprev = ((bal << 1) >> lane) & 1ull;
                        Ld[p] = cond ? (cprev ? pd : v)  : Ld[p];
                        Li[p] = cond ? (cprev ? pi : mi) : Li[p];
                        kth[p] = __shfl(Ld[p], 15);
                    }
                }
            }
        }
    }

    // epilogue: recompute exact subtract-form dists for the winners, store
#pragma unroll
    for (int p = 0; p < PTS_PER_WAVE; ++p) {
        int pt = base_pt + p;
        if (pt >= N_PTS) continue;                 // uniform guard
        int ii = Li[p];                            // valid in lanes 0..15 (always <M_PAD)
        float4 a = yp[ii];
        float dx = px[p] - a.x, dy = py[p] - a.y, dz = pz[p] - a.z;
        float dist = (dx*dx + dy*dy) + dz*dz;      // ((x-y)**2).sum(-1) order
        if (lane < KNN) {
            oidx [pt * KNN + lane] = ii;
            odist[pt * KNN + lane] = dist;
        }
    }
}

// ---------------- per-atom precompute: A[l][i][j] = feats[i] @ W1[l][64:128] + b1[l] ----------------
// 8 atoms per wave share each W1-row load (8x less L2 traffic than 1 atom/wave).
#define ATOMS_PER_WAVE 8
#define A_GROUPS (M_ATOMS / ATOMS_PER_WAVE)        // 1250
__global__ __launch_bounds__(256) void precompute_A_kernel(
        const float* __restrict__ feats, const float* __restrict__ W1,
        const float* __restrict__ b1, float* __restrict__ A) {
    int wid = threadIdx.x >> 6, lane = threadIdx.x & 63;
    int id = blockIdx.x * 4 + wid;                 // 0 .. NLAYERS*A_GROUPS-1
    if (id >= NLAYERS * A_GROUPS) return;
    int l = id / A_GROUPS, g = id - l * A_GROUPS;
    int base_atom = g * ATOMS_PER_WAVE;

    float f[ATOMS_PER_WAVE];
#pragma unroll
    for (int a = 0; a < ATOMS_PER_WAVE; ++a) f[a] = feats[(base_atom + a) * DAT + lane];

    float a0[ATOMS_PER_WAVE], a1[ATOMS_PER_WAVE], a2[ATOMS_PER_WAVE];
#pragma unroll
    for (int a = 0; a < ATOMS_PER_WAVE; ++a) { a0[a] = 0.f; a1[a] = 0.f; a2[a] = 0.f; }

    const float* Wl = W1 + (size_t)l * HID * HID;
#pragma unroll 4
    for (int d = 0; d < DAT; ++d) {
        const float* row = Wl + (64 + d) * HID;    // feats rows of W1
        float w0 = row[lane];
        float w1 = row[64 + lane];
        float w2 = row[128];
#pragma unroll
        for (int a = 0; a < ATOMS_PER_WAVE; ++a) {
            float s = __shfl(f[a], d);
            a0[a] += s * w0;
            a1[a] += s * w1;
            a2[a] += s * w2;
        }
    }
    const float* b1l = b1 + l * HID;
    float bb0 = b1l[lane], bb1 = b1l[64 + lane], bb2 = b1l[128];
#pragma unroll
    for (int a = 0; a < ATOMS_PER_WAVE; ++a) {
        float* Ar = A + ((size_t)l * M_ATOMS + base_atom + a) * A_STRIDE;
        Ar[lane]      = a0[a] + bb0;
        Ar[64 + lane] = a1[a] + bb1;
        if (lane == 0) Ar[128] = a2[a] + bb2;
    }
}

// ---------------- fused 3-layer MLP + groupnorm, one wave per point ----------------
__global__ __launch_bounds__(256) void mlp_kernel(
        const float* __restrict__ W1, const float* __restrict__ W2,
        const float* __restrict__ b2, const float* __restrict__ gnw,
        const float* __restrict__ gnb, const float* __restrict__ A,
        const int* __restrict__ oidx, const float* __restrict__ odist,
        float* __restrict__ out) {
    int wid = threadIdx.x >> 6, lane = threadIdx.x & 63;
    int n = blockIdx.x * 4 + wid;
    if (n >= N_PTS) return;

    float pe = 1.0f;                               // point_emb init ones
    int   ikl = 0; float dkl = 0.f;
    if (lane < KNN) { ikl = oidx[n * KNN + lane]; dkl = odist[n * KNN + lane]; }
    int ii[KNN]; float dd[KNN];
#pragma unroll
    for (int k = 0; k < KNN; ++k) { ii[k] = __shfl(ikl, k); dd[k] = __shfl(dkl, k); }

    for (int l = 0; l < NLAYERS; ++l) {
        const float* Wl = W1 + (size_t)l * HID * HID;

        // prefetch gathered A rows into registers: loads issue here, latency
        // is covered by the 64-iteration p-matmul below.
        float Av0[KNN], Av1[KNN], Av2[KNN];
#pragma unroll
        for (int k = 0; k < KNN; ++k) {
            const float* Ar = A + ((size_t)l * M_ATOMS + ii[k]) * A_STRIDE;
            Av0[k] = Ar[lane];
            Av1[k] = Ar[64 + lane];
            Av2[k] = Ar[128];
        }

        // p = pe @ W1[l][0:64]  (k-independent part); lane covers dims lane, 64+lane, 128
        float p0 = 0.f, p1 = 0.f, p2 = 0.f;
#pragma unroll 8
        for (int d = 0; d < DAT; ++d) {
            float s = __shfl(pe, d);
            const float* row = Wl + d * HID;
            p0 += s * row[lane];
            p1 += s * row[64 + lane];
            p2 += s * row[128];
        }
        const float* wl = Wl + 128 * HID;          // dist row of W1
        float wl0 = wl[lane], wl1 = wl[64 + lane], wl2 = wl[128];

        // hsum = sum_k leaky(p + A[idx_k] + dist_k * wl)
        float hs0 = 0.f, hs1 = 0.f, hs2 = 0.f;
#pragma unroll
        for (int k = 0; k < KNN; ++k) {
            float h0 = p0 + Av0[k] + dd[k] * wl0; h0 = h0 >= 0.f ? h0 : 0.2f * h0; hs0 += h0;
            float h1 = p1 + Av1[k] + dd[k] * wl1; h1 = h1 >= 0.f ? h1 : 0.2f * h1; hs1 += h1;
            float h2 = p2 + Av2[k] + dd[k] * wl2; h2 = h2 >= 0.f ? h2 : 0.2f * h2; hs2 += h2;
        }

        // msg = hsum @ W2[l] + K*b2[l]   (sum over k hoisted before the matmul)
        const float* W2l = W2 + (size_t)l * HID * DAT;
        float m = 0.f;
#pragma unroll 8
        for (int j = 0; j < DAT; ++j) {
            float a0 = __shfl(hs0, j), a1 = __shfl(hs1, j);
            m += a0 * W2l[j * DAT + lane];
            m += a1 * W2l[(64 + j) * DAT + lane];
        }
        m += hs2 * W2l[128 * DAT + lane];
        m += 16.f * b2[l * DAT + lane];

        // GroupNorm(2 groups of 32 channels) — reduce within aligned 32-lane halves
        float s1 = m;
        s1 += __shfl_xor(s1, 1);  s1 += __shfl_xor(s1, 2);  s1 += __shfl_xor(s1, 4);
        s1 += __shfl_xor(s1, 8);  s1 += __shfl_xor(s1, 16);
        float mu = s1 * (1.f / 32.f);
        float dm = m - mu;
        float s2 = dm * dm;
        s2 += __shfl_xor(s2, 1);  s2 += __shfl_xor(s2, 2);  s2 += __shfl_xor(s2, 4);
        s2 += __shfl_xor(s2, 8);  s2 += __shfl_xor(s2, 16);
        float var = s2 * (1.f / 32.f);
        float g = dm * (1.f / sqrtf(var + 1e-5f)) * gnw[l * DAT + lane] + gnb[l * DAT + lane];
        pe += (g >= 0.f) ? g : 0.2f * g;           // leaky, residual add
    }
    out[n * DAT + lane] = pe;
}

// ---------------- launch ----------------
extern "C" void kernel_launch(void* const* d_in, const int* in_sizes, int n_in,
                              void* d_out, int out_size, void* d_ws, size_t ws_size,
                              hipStream_t stream) {
    const float* x     = (const float*)d_in[0];
    const float* y     = (const float*)d_in[1];
    const float* feats = (const float*)d_in[2];
    const float* W1    = (const float*)d_in[3];
    const float* b1    = (const float*)d_in[4];
    const float* W2    = (const float*)d_in[5];
    const float* b2    = (const float*)d_in[6];
    const float* gnw   = (const float*)d_in[7];
    const float* gnb   = (const float*)d_in[8];
    float* out = (float*)d_out;

    char* ws = (char*)d_ws;
    float4* yp   = (float4*)ws;                         // 10240*16     = 163,840 B
    int*    oidx = (int*)  (ws + 163840);               // 20000*16*4   = 1,280,000 B
    float*  odist= (float*)(ws + 163840 + 1280000);     // 1,280,000 B
    float*  A    = (float*)(ws + 163840 + 2560000);     // 3*10000*132*4 = 15,840,000 B
    // total ~18.6 MB of ws

    pack_y_kernel<<<dim3((M_PAD + 255) / 256), dim3(256), 0, stream>>>(y, yp);
    knn_kernel<<<dim3(N_PTS / PTS_PER_BLOCK), dim3(256), 0, stream>>>(x, yp, oidx, odist);
    precompute_A_kernel<<<dim3((NLAYERS * A_GROUPS + 3) / 4), dim3(256), 0, stream>>>(feats, W1, b1, A);
    mlp_kernel<<<dim3(N_PTS / 4), dim3(256), 0, stream>>>(W1, W2, b2, gnw, gnb, A, oidx, odist, out);
}

// Round 3
// 458.044 us; speedup vs baseline: 1.5400x; 1.5400x over previous
//
#include <hip/hip_runtime.h>

#define N_PTS   20000
#define M_ATOMS 10000
#define DAT     64
#define HID     129
#define KNN     16
#define NLAYERS 3

#define TILE_ATOMS 2048
#define NTILES     5          // 5*2048 = 10240 >= 10000
#define M_PAD      10240
#define A_HSTRIDE  132        // A row stride in HALVES (264 B, 8B-aligned)
#define PTS_PER_WAVE  4
#define PTS_PER_BLOCK 16      // 4 waves * 4

typedef _Float16 half2_t __attribute__((ext_vector_type(2)));

// ---------------- pack y -> float4(x,y,z,|y|^2), INF-padded ----------------
__global__ void pack_y_kernel(const float* __restrict__ y, float4* __restrict__ yp) {
    int i = blockIdx.x * blockDim.x + threadIdx.x;
    if (i >= M_PAD) return;
    if (i < M_ATOMS) {
        float a = y[3*i], b = y[3*i+1], c = y[3*i+2];
        float s = (a*a + b*b) + c*c;          // same order as (y**2).sum(1)
        yp[i] = make_float4(a, b, c, s);
    } else {
        yp[i] = make_float4(0.f, 0.f, 0.f, __builtin_inff());  // pad -> d2=INF
    }
}

// ---------------- brute-force exact kNN (K=16) ----------------
__global__ __launch_bounds__(256) void knn_kernel(
        const float* __restrict__ x, const float4* __restrict__ yp,
        int* __restrict__ oidx, float* __restrict__ odist) {
    __shared__ float4 tile[TILE_ATOMS];     // 32 KiB
    const int tid  = threadIdx.x;
    const int lane = tid & 63;
    const int wid  = tid >> 6;
    const int base_pt = blockIdx.x * PTS_PER_BLOCK + wid * PTS_PER_WAVE;
    const float INF = __builtin_inff();

    float rx0 = 0.f, rx1 = 0.f, rx2 = 0.f, rx3 = 0.f;
    if (lane < PTS_PER_WAVE) {
        int pt = base_pt + lane;
        if (pt < N_PTS) {
            rx0 = x[3*pt]; rx1 = x[3*pt+1]; rx2 = x[3*pt+2];
            rx3 = (rx0*rx0 + rx1*rx1) + rx2*rx2;   // (x**2).sum(1) order
        }
    }
    float px[PTS_PER_WAVE], py[PTS_PER_WAVE], pz[PTS_PER_WAVE], ps[PTS_PER_WAVE];
#pragma unroll
    for (int p = 0; p < PTS_PER_WAVE; ++p) {
        px[p] = __shfl(rx0, p); py[p] = __shfl(rx1, p);
        pz[p] = __shfl(rx2, p); ps[p] = __shfl(rx3, p);
    }

    float Ld[PTS_PER_WAVE];  int Li[PTS_PER_WAVE];  float kth[PTS_PER_WAVE];
#pragma unroll
    for (int p = 0; p < PTS_PER_WAVE; ++p) { Ld[p] = INF; Li[p] = 0; kth[p] = INF; }

    for (int t = 0; t < NTILES; ++t) {
        __syncthreads();
        for (int j = tid; j < TILE_ATOMS; j += 256) tile[j] = yp[t * TILE_ATOMS + j];
        __syncthreads();
        const int abase = t * TILE_ATOMS;
#pragma unroll 2
        for (int it = 0; it < TILE_ATOMS / 64; ++it) {
            float4 a = tile[it * 64 + lane];        // read ONCE, serve 4 points
            const int cbase = abase + it * 64;
#pragma unroll
            for (int p = 0; p < PTS_PER_WAVE; ++p) {
                // selection metric in the SAME algebra as reference: (x2 - 2*dot) + y2
                float dot = (px[p] * a.x + py[p] * a.y) + pz[p] * a.z;
                float d2  = (ps[p] - 2.f * dot) + a.w;
                unsigned long long mask = __ballot(d2 < kth[p]);
                while (mask) {                      // uniform loop
                    int src = __builtin_ctzll(mask);  // ascending atom index
                    mask &= mask - 1;
                    float v = __shfl(d2, src);
                    if (v < kth[p]) {               // recheck vs updated kth
                        int mi = cbase + src;
                        bool cond = Ld[p] > v;      // strict: stable ties (lower idx first)
                        unsigned long long bal = __ballot(cond);
                        float pd = __shfl_up(Ld[p], 1);
                        int   pi = __shfl_up(Li[p], 1);
                        bool cprev = ((bal << 1) >> lane) & 1ull;
                        Ld[p] = cond ? (cprev ? pd : v)  : Ld[p];
                        Li[p] = cond ? (cprev ? pi : mi) : Li[p];
                        kth[p] = __shfl(Ld[p], 15);
                    }
                }
            }
        }
    }

#pragma unroll
    for (int p = 0; p < PTS_PER_WAVE; ++p) {
        int pt = base_pt + p;
        if (pt >= N_PTS) continue;
        int ii = Li[p];
        float4 a = yp[ii];
        float dx = px[p] - a.x, dy = py[p] - a.y, dz = pz[p] - a.z;
        float dist = (dx*dx + dy*dy) + dz*dz;      // ((x-y)**2).sum(-1) order
        if (lane < KNN) {
            oidx [pt * KNN + lane] = ii;
            odist[pt * KNN + lane] = dist;
        }
    }
}

// ---------------- per-atom precompute: A[l][i] = feats[i] @ W1[l][64:128] + b1[l] (fp16) ----------------
// Channel remap: lane owns HID channels (2*lane, 2*lane+1); channel 128 separate.
#define ATOMS_PER_WAVE 8
#define A_GROUPS (M_ATOMS / ATOMS_PER_WAVE)        // 1250
__global__ __launch_bounds__(256) void precompute_A_kernel(
        const float* __restrict__ feats, const float* __restrict__ W1,
        const float* __restrict__ b1, _Float16* __restrict__ A) {
    int wid = threadIdx.x >> 6, lane = threadIdx.x & 63;
    int id = blockIdx.x * 4 + wid;
    if (id >= NLAYERS * A_GROUPS) return;
    int l = id / A_GROUPS, g = id - l * A_GROUPS;
    int base_atom = g * ATOMS_PER_WAVE;

    float f[ATOMS_PER_WAVE];
#pragma unroll
    for (int a = 0; a < ATOMS_PER_WAVE; ++a) f[a] = feats[(base_atom + a) * DAT + lane];

    float a0[ATOMS_PER_WAVE], a1[ATOMS_PER_WAVE], a2[ATOMS_PER_WAVE];
#pragma unroll
    for (int a = 0; a < ATOMS_PER_WAVE; ++a) { a0[a] = 0.f; a1[a] = 0.f; a2[a] = 0.f; }

    const float* Wl = W1 + (size_t)l * HID * HID;
#pragma unroll 4
    for (int d = 0; d < DAT; ++d) {
        const float* row = Wl + (64 + d) * HID;    // feats rows of W1
        float w0 = row[2 * lane];
        float w1 = row[2 * lane + 1];
        float w2 = row[128];
#pragma unroll
        for (int a = 0; a < ATOMS_PER_WAVE; ++a) {
            float s = __shfl(f[a], d);
            a0[a] += s * w0;
            a1[a] += s * w1;
            a2[a] += s * w2;
        }
    }
    const float* b1l = b1 + l * HID;
    float bb0 = b1l[2 * lane], bb1 = b1l[2 * lane + 1], bb2 = b1l[128];
#pragma unroll
    for (int a = 0; a < ATOMS_PER_WAVE; ++a) {
        _Float16* Ar = A + ((size_t)l * M_ATOMS + base_atom + a) * A_HSTRIDE;
        half2_t hv; hv.x = (_Float16)(a0[a] + bb0); hv.y = (_Float16)(a1[a] + bb1);
        ((half2_t*)Ar)[lane] = hv;
        if (lane == 0) Ar[128] = (_Float16)(a2[a] + bb2);
    }
}

// ---------------- one layer of the MLP + groupnorm, one wave per point ----------------
// Per-layer launch => exactly one 2.64 MB A-slice hot in L2 at a time.
template<bool FIRST, bool LAST>
__global__ __launch_bounds__(256) void layer_kernel(
        int l,
        const float* __restrict__ W1, const float* __restrict__ W2,
        const float* __restrict__ b2, const float* __restrict__ gnw,
        const float* __restrict__ gnb, const _Float16* __restrict__ A,
        const int* __restrict__ oidx, const float* __restrict__ odist,
        float* __restrict__ pe_buf, float* __restrict__ out) {
    int wid = threadIdx.x >> 6, lane = threadIdx.x & 63;
    int n = blockIdx.x * 4 + wid;                  // 5000*4 == 20000 exact

    float pe = FIRST ? 1.0f : pe_buf[n * DAT + lane];
    int   ikl = 0; float dkl = 0.f;
    if (lane < KNN) { ikl = oidx[n * KNN + lane]; dkl = odist[n * KNN + lane]; }
    int ii[KNN]; float dd[KNN];
#pragma unroll
    for (int k = 0; k < KNN; ++k) { ii[k] = __shfl(ikl, k); dd[k] = __shfl(dkl, k); }

    // prefetch gathered fp16 A rows (one coalesced 256B load + one scalar each);
    // latency covered by the 64-iteration p-matmul below.
    half2_t Av01[KNN]; _Float16 Av2[KNN];
#pragma unroll
    for (int k = 0; k < KNN; ++k) {
        const _Float16* Ar = A + ((size_t)l * M_ATOMS + ii[k]) * A_HSTRIDE;
        Av01[k] = ((const half2_t*)Ar)[lane];
        Av2[k]  = Ar[128];
    }

    const float* Wl = W1 + (size_t)l * HID * HID;
    // p = pe @ W1[l][0:64]; lane owns HID channels (2*lane, 2*lane+1), plus 128
    float p0 = 0.f, p1 = 0.f, p2 = 0.f;
#pragma unroll 8
    for (int d = 0; d < DAT; ++d) {
        float s = __shfl(pe, d);
        const float* row = Wl + d * HID;
        p0 += s * row[2 * lane];
        p1 += s * row[2 * lane + 1];
        p2 += s * row[128];
    }
    const float* wl = Wl + 128 * HID;              // dist row of W1
    float wl0 = wl[2 * lane], wl1 = wl[2 * lane + 1], wl2 = wl[128];

    // hsum = sum_k leaky(p + A[idx_k] + dist_k * wl)
    float hs0 = 0.f, hs1 = 0.f, hs2 = 0.f;
#pragma unroll
    for (int k = 0; k < KNN; ++k) {
        float A0 = (float)Av01[k].x, A1 = (float)Av01[k].y, A2 = (float)Av2[k];
        float h0 = p0 + A0 + dd[k] * wl0; h0 = h0 >= 0.f ? h0 : 0.2f * h0; hs0 += h0;
        float h1 = p1 + A1 + dd[k] * wl1; h1 = h1 >= 0.f ? h1 : 0.2f * h1; hs1 += h1;
        float h2 = p2 + A2 + dd[k] * wl2; h2 = h2 >= 0.f ? h2 : 0.2f * h2; hs2 += h2;
    }

    // msg = hsum @ W2[l] + K*b2[l]  (sum over k hoisted before the matmul)
    const float* W2l = W2 + (size_t)l * HID * DAT;
    float m = 0.f;
#pragma unroll 8
    for (int j = 0; j < DAT; ++j) {
        float a0 = __shfl(hs0, j), a1 = __shfl(hs1, j);
        m += a0 * W2l[(2 * j) * DAT + lane];
        m += a1 * W2l[(2 * j + 1) * DAT + lane];
    }
    m += hs2 * W2l[128 * DAT + lane];
    m += 16.f * b2[l * DAT + lane];

    // GroupNorm(2 groups of 32 channels) — reduce within aligned 32-lane halves
    float s1 = m;
    s1 += __shfl_xor(s1, 1);  s1 += __shfl_xor(s1, 2);  s1 += __shfl_xor(s1, 4);
    s1 += __shfl_xor(s1, 8);  s1 += __shfl_xor(s1, 16);
    float mu = s1 * (1.f / 32.f);
    float dm = m - mu;
    float s2 = dm * dm;
    s2 += __shfl_xor(s2, 1);  s2 += __shfl_xor(s2, 2);  s2 += __shfl_xor(s2, 4);
    s2 += __shfl_xor(s2, 8);  s2 += __shfl_xor(s2, 16);
    float var = s2 * (1.f / 32.f);
    float g = dm * (1.f / sqrtf(var + 1e-5f)) * gnw[l * DAT + lane] + gnb[l * DAT + lane];
    pe += (g >= 0.f) ? g : 0.2f * g;               // leaky, residual add

    if (LAST) out[n * DAT + lane] = pe;
    else      pe_buf[n * DAT + lane] = pe;
}

// ---------------- launch ----------------
extern "C" void kernel_launch(void* const* d_in, const int* in_sizes, int n_in,
                              void* d_out, int out_size, void* d_ws, size_t ws_size,
                              hipStream_t stream) {
    const float* x     = (const float*)d_in[0];
    const float* y     = (const float*)d_in[1];
    const float* feats = (const float*)d_in[2];
    const float* W1    = (const float*)d_in[3];
    const float* b1    = (const float*)d_in[4];
    const float* W2    = (const float*)d_in[5];
    const float* b2    = (const float*)d_in[6];
    const float* gnw   = (const float*)d_in[7];
    const float* gnb   = (const float*)d_in[8];
    float* out = (float*)d_out;

    char* ws = (char*)d_ws;
    float4*    yp    = (float4*)ws;                       // 10240*16        = 163,840 B
    int*       oidx  = (int*)   (ws + 163840);            // 20000*16*4      = 1,280,000 B
    float*     odist = (float*) (ws + 163840 + 1280000);  // 1,280,000 B
    _Float16*  A     = (_Float16*)(ws + 2723840);         // 3*10000*132*2   = 7,920,000 B
    float*     pe_buf= (float*) (ws + 2723840 + 7920000); // 20000*64*4      = 5,120,000 B
    // total ~15.8 MB of ws

    pack_y_kernel<<<dim3((M_PAD + 255) / 256), dim3(256), 0, stream>>>(y, yp);
    knn_kernel<<<dim3(N_PTS / PTS_PER_BLOCK), dim3(256), 0, stream>>>(x, yp, oidx, odist);
    precompute_A_kernel<<<dim3((NLAYERS * A_GROUPS + 3) / 4), dim3(256), 0, stream>>>(feats, W1, b1, A);
    layer_kernel<true,  false><<<dim3(N_PTS / 4), dim3(256), 0, stream>>>(0, W1, W2, b2, gnw, gnb, A, oidx, odist, pe_buf, out);
    layer_kernel<false, false><<<dim3(N_PTS / 4), dim3(256), 0, stream>>>(1, W1, W2, b2, gnw, gnb, A, oidx, odist, pe_buf, out);
    layer_kernel<false, true ><<<dim3(N_PTS / 4), dim3(256), 0, stream>>>(2, W1, W2, b2, gnw, gnb, A, oidx, odist, pe_buf, out);
}

// Round 4
// 398.941 us; speedup vs baseline: 1.7682x; 1.1481x over previous
//
#include <hip/hip_runtime.h>

#define N_PTS   20000
#define M_ATOMS 10000
#define DAT     64
#define HID     129
#define KNN     16
#define NLAYERS 3

#define TILE_ATOMS 1024
#define NTILES     10         // 10*1024 = 10240 >= 10000
#define M_PAD      10240
#define A_HSTRIDE  132        // A row stride in HALVES (264 B, 8B-aligned)
#define PTS_PER_WAVE  2
#define PTS_PER_BLOCK 8       // 4 waves * 2

typedef _Float16 half2_t __attribute__((ext_vector_type(2)));

// ---------------- pack y -> float4(x,y,z,|y|^2), INF-padded ----------------
__global__ void pack_y_kernel(const float* __restrict__ y, float4* __restrict__ yp) {
    int i = blockIdx.x * blockDim.x + threadIdx.x;
    if (i >= M_PAD) return;
    if (i < M_ATOMS) {
        float a = y[3*i], b = y[3*i+1], c = y[3*i+2];
        float s = (a*a + b*b) + c*c;          // same order as (y**2).sum(1)
        yp[i] = make_float4(a, b, c, s);
    } else {
        yp[i] = make_float4(0.f, 0.f, 0.f, __builtin_inff());  // pad -> d2=INF
    }
}

// ---------------- brute-force exact kNN (K=16) ----------------
// 2 points/wave -> 10000 waves (fills the machine's 8192 wave slots).
// Top-16 held distributed in lanes 0..15 sorted ascending; insert via
// ballot + shfl_up shift. kth broadcast hoisted to once per 64-batch
// (stale kth is a valid upper bound -> exactness preserved).
__global__ __launch_bounds__(256) void knn_kernel(
        const float* __restrict__ x, const float4* __restrict__ yp,
        int* __restrict__ oidx, float* __restrict__ odist) {
    __shared__ float4 tile[TILE_ATOMS];     // 16 KiB -> 8 blocks/CU
    const int tid  = threadIdx.x;
    const int lane = tid & 63;
    const int wid  = tid >> 6;
    const int base_pt = blockIdx.x * PTS_PER_BLOCK + wid * PTS_PER_WAVE;
    const float INF = __builtin_inff();

    float rx0 = 0.f, rx1 = 0.f, rx2 = 0.f, rx3 = 0.f;
    if (lane < PTS_PER_WAVE) {
        int pt = base_pt + lane;
        if (pt < N_PTS) {
            rx0 = x[3*pt]; rx1 = x[3*pt+1]; rx2 = x[3*pt+2];
            rx3 = (rx0*rx0 + rx1*rx1) + rx2*rx2;   // (x**2).sum(1) order
        }
    }
    float px[PTS_PER_WAVE], py[PTS_PER_WAVE], pz[PTS_PER_WAVE], ps[PTS_PER_WAVE];
#pragma unroll
    for (int p = 0; p < PTS_PER_WAVE; ++p) {
        px[p] = __shfl(rx0, p); py[p] = __shfl(rx1, p);
        pz[p] = __shfl(rx2, p); ps[p] = __shfl(rx3, p);
    }

    float Ld[PTS_PER_WAVE];  int Li[PTS_PER_WAVE];  float kth[PTS_PER_WAVE];
#pragma unroll
    for (int p = 0; p < PTS_PER_WAVE; ++p) { Ld[p] = INF; Li[p] = 0; kth[p] = INF; }

    for (int t = 0; t < NTILES; ++t) {
        __syncthreads();
        for (int j = tid; j < TILE_ATOMS; j += 256) tile[j] = yp[t * TILE_ATOMS + j];
        __syncthreads();
        const int abase = t * TILE_ATOMS;
#pragma unroll 2
        for (int it = 0; it < TILE_ATOMS / 64; ++it) {
            float4 a = tile[it * 64 + lane];        // read ONCE, serve both points
            const int cbase = abase + it * 64;
#pragma unroll
            for (int p = 0; p < PTS_PER_WAVE; ++p) {
                // selection metric in the SAME algebra as reference: (x2 - 2*dot) + y2
                float dot = (px[p] * a.x + py[p] * a.y) + pz[p] * a.z;
                float d2  = (ps[p] - 2.f * dot) + a.w;
                unsigned long long mask = __ballot(d2 < kth[p]);
                if (mask) {
                    do {                                // uniform loop
                        int src = __builtin_ctzll(mask);  // ascending atom index
                        mask &= mask - 1;
                        float v = __shfl(d2, src);
                        if (v < kth[p]) {               // stale-kth recheck (safe)
                            int mi = cbase + src;
                            bool cond = Ld[p] > v;      // strict: stable ties (lower idx first)
                            unsigned long long bal = __ballot(cond);
                            float pd = __shfl_up(Ld[p], 1);
                            int   pi = __shfl_up(Li[p], 1);
                            bool cprev = ((bal << 1) >> lane) & 1ull;
                            Ld[p] = cond ? (cprev ? pd : v)  : Ld[p];
                            Li[p] = cond ? (cprev ? pi : mi) : Li[p];
                        }
                    } while (mask);
                    kth[p] = __shfl(Ld[p], 15);         // once per batch, off chain
                }
            }
        }
    }

#pragma unroll
    for (int p = 0; p < PTS_PER_WAVE; ++p) {
        int pt = base_pt + p;
        if (pt >= N_PTS) continue;
        int ii = Li[p];
        float4 a = yp[ii];
        float dx = px[p] - a.x, dy = py[p] - a.y, dz = pz[p] - a.z;
        float dist = (dx*dx + dy*dy) + dz*dz;      // ((x-y)**2).sum(-1) order
        if (lane < KNN) {
            oidx [pt * KNN + lane] = ii;
            odist[pt * KNN + lane] = dist;
        }
    }
}

// ---------------- per-atom precompute: A[l][i] = feats[i] @ W1[l][64:128] + b1[l] (fp16) ----------------
// Channel remap: lane owns HID channels (2*lane, 2*lane+1); channel 128 separate.
#define ATOMS_PER_WAVE 8
#define A_GROUPS (M_ATOMS / ATOMS_PER_WAVE)        // 1250
__global__ __launch_bounds__(256) void precompute_A_kernel(
        const float* __restrict__ feats, const float* __restrict__ W1,
        const float* __restrict__ b1, _Float16* __restrict__ A) {
    int wid = threadIdx.x >> 6, lane = threadIdx.x & 63;
    int id = blockIdx.x * 4 + wid;
    if (id >= NLAYERS * A_GROUPS) return;
    int l = id / A_GROUPS, g = id - l * A_GROUPS;
    int base_atom = g * ATOMS_PER_WAVE;

    float f[ATOMS_PER_WAVE];
#pragma unroll
    for (int a = 0; a < ATOMS_PER_WAVE; ++a) f[a] = feats[(base_atom + a) * DAT + lane];

    float a0[ATOMS_PER_WAVE], a1[ATOMS_PER_WAVE], a2[ATOMS_PER_WAVE];
#pragma unroll
    for (int a = 0; a < ATOMS_PER_WAVE; ++a) { a0[a] = 0.f; a1[a] = 0.f; a2[a] = 0.f; }

    const float* Wl = W1 + (size_t)l * HID * HID;
#pragma unroll 4
    for (int d = 0; d < DAT; ++d) {
        const float* row = Wl + (64 + d) * HID;    // feats rows of W1
        float w0 = row[2 * lane];
        float w1 = row[2 * lane + 1];
        float w2 = row[128];
#pragma unroll
        for (int a = 0; a < ATOMS_PER_WAVE; ++a) {
            float s = __shfl(f[a], d);
            a0[a] += s * w0;
            a1[a] += s * w1;
            a2[a] += s * w2;
        }
    }
    const float* b1l = b1 + l * HID;
    float bb0 = b1l[2 * lane], bb1 = b1l[2 * lane + 1], bb2 = b1l[128];
#pragma unroll
    for (int a = 0; a < ATOMS_PER_WAVE; ++a) {
        _Float16* Ar = A + ((size_t)l * M_ATOMS + base_atom + a) * A_HSTRIDE;
        half2_t hv; hv.x = (_Float16)(a0[a] + bb0); hv.y = (_Float16)(a1[a] + bb1);
        ((half2_t*)Ar)[lane] = hv;
        if (lane == 0) Ar[128] = (_Float16)(a2[a] + bb2);
    }
}

// ---------------- one layer of the MLP + groupnorm, one wave per point ----------------
// Per-layer launch => exactly one 2.64 MB A-slice hot in L2 at a time.
template<bool FIRST, bool LAST>
__global__ __launch_bounds__(256) void layer_kernel(
        int l,
        const float* __restrict__ W1, const float* __restrict__ W2,
        const float* __restrict__ b2, const float* __restrict__ gnw,
        const float* __restrict__ gnb, const _Float16* __restrict__ A,
        const int* __restrict__ oidx, const float* __restrict__ odist,
        float* __restrict__ pe_buf, float* __restrict__ out) {
    int wid = threadIdx.x >> 6, lane = threadIdx.x & 63;
    int n = blockIdx.x * 4 + wid;                  // 5000*4 == 20000 exact

    float pe = FIRST ? 1.0f : pe_buf[n * DAT + lane];
    int   ikl = 0; float dkl = 0.f;
    if (lane < KNN) { ikl = oidx[n * KNN + lane]; dkl = odist[n * KNN + lane]; }
    int ii[KNN]; float dd[KNN];
#pragma unroll
    for (int k = 0; k < KNN; ++k) { ii[k] = __shfl(ikl, k); dd[k] = __shfl(dkl, k); }

    // prefetch gathered fp16 A rows (one coalesced 256B load + one scalar each);
    // latency covered by the 64-iteration p-matmul below.
    half2_t Av01[KNN]; _Float16 Av2[KNN];
#pragma unroll
    for (int k = 0; k < KNN; ++k) {
        const _Float16* Ar = A + ((size_t)l * M_ATOMS + ii[k]) * A_HSTRIDE;
        Av01[k] = ((const half2_t*)Ar)[lane];
        Av2[k]  = Ar[128];
    }

    const float* Wl = W1 + (size_t)l * HID * HID;
    // p = pe @ W1[l][0:64]; lane owns HID channels (2*lane, 2*lane+1), plus 128
    float p0 = 0.f, p1 = 0.f, p2 = 0.f;
#pragma unroll 8
    for (int d = 0; d < DAT; ++d) {
        float s = __shfl(pe, d);
        const float* row = Wl + d * HID;
        p0 += s * row[2 * lane];
        p1 += s * row[2 * lane + 1];
        p2 += s * row[128];
    }
    const float* wl = Wl + 128 * HID;              // dist row of W1
    float wl0 = wl[2 * lane], wl1 = wl[2 * lane + 1], wl2 = wl[128];

    // hsum = sum_k leaky(p + A[idx_k] + dist_k * wl)
    float hs0 = 0.f, hs1 = 0.f, hs2 = 0.f;
#pragma unroll
    for (int k = 0; k < KNN; ++k) {
        float A0 = (float)Av01[k].x, A1 = (float)Av01[k].y, A2 = (float)Av2[k];
        float h0 = p0 + A0 + dd[k] * wl0; h0 = h0 >= 0.f ? h0 : 0.2f * h0; hs0 += h0;
        float h1 = p1 + A1 + dd[k] * wl1; h1 = h1 >= 0.f ? h1 : 0.2f * h1; hs1 += h1;
        float h2 = p2 + A2 + dd[k] * wl2; h2 = h2 >= 0.f ? h2 : 0.2f * h2; hs2 += h2;
    }

    // msg = hsum @ W2[l] + K*b2[l]  (sum over k hoisted before the matmul)
    const float* W2l = W2 + (size_t)l * HID * DAT;
    float m = 0.f;
#pragma unroll 8
    for (int j = 0; j < DAT; ++j) {
        float a0 = __shfl(hs0, j), a1 = __shfl(hs1, j);
        m += a0 * W2l[(2 * j) * DAT + lane];
        m += a1 * W2l[(2 * j + 1) * DAT + lane];
    }
    m += hs2 * W2l[128 * DAT + lane];
    m += 16.f * b2[l * DAT + lane];

    // GroupNorm(2 groups of 32 channels) — reduce within aligned 32-lane halves
    float s1 = m;
    s1 += __shfl_xor(s1, 1);  s1 += __shfl_xor(s1, 2);  s1 += __shfl_xor(s1, 4);
    s1 += __shfl_xor(s1, 8);  s1 += __shfl_xor(s1, 16);
    float mu = s1 * (1.f / 32.f);
    float dm = m - mu;
    float s2 = dm * dm;
    s2 += __shfl_xor(s2, 1);  s2 += __shfl_xor(s2, 2);  s2 += __shfl_xor(s2, 4);
    s2 += __shfl_xor(s2, 8);  s2 += __shfl_xor(s2, 16);
    float var = s2 * (1.f / 32.f);
    float g = dm * (1.f / sqrtf(var + 1e-5f)) * gnw[l * DAT + lane] + gnb[l * DAT + lane];
    pe += (g >= 0.f) ? g : 0.2f * g;               // leaky, residual add

    if (LAST) out[n * DAT + lane] = pe;
    else      pe_buf[n * DAT + lane] = pe;
}

// ---------------- launch ----------------
extern "C" void kernel_launch(void* const* d_in, const int* in_sizes, int n_in,
                              void* d_out, int out_size, void* d_ws, size_t ws_size,
                              hipStream_t stream) {
    const float* x     = (const float*)d_in[0];
    const float* y     = (const float*)d_in[1];
    const float* feats = (const float*)d_in[2];
    const float* W1    = (const float*)d_in[3];
    const float* b1    = (const float*)d_in[4];
    const float* W2    = (const float*)d_in[5];
    const float* b2    = (const float*)d_in[6];
    const float* gnw   = (const float*)d_in[7];
    const float* gnb   = (const float*)d_in[8];
    float* out = (float*)d_out;

    char* ws = (char*)d_ws;
    float4*    yp    = (float4*)ws;                       // 10240*16        = 163,840 B
    int*       oidx  = (int*)   (ws + 163840);            // 20000*16*4      = 1,280,000 B
    float*     odist = (float*) (ws + 163840 + 1280000);  // 1,280,000 B
    _Float16*  A     = (_Float16*)(ws + 2723840);         // 3*10000*132*2   = 7,920,000 B
    float*     pe_buf= (float*) (ws + 2723840 + 7920000); // 20000*64*4      = 5,120,000 B
    // total ~15.8 MB of ws

    pack_y_kernel<<<dim3((M_PAD + 255) / 256), dim3(256), 0, stream>>>(y, yp);
    knn_kernel<<<dim3(N_PTS / PTS_PER_BLOCK), dim3(256), 0, stream>>>(x, yp, oidx, odist);
    precompute_A_kernel<<<dim3((NLAYERS * A_GROUPS + 3) / 4), dim3(256), 0, stream>>>(feats, W1, b1, A);
    layer_kernel<true,  false><<<dim3(N_PTS / 4), dim3(256), 0, stream>>>(0, W1, W2, b2, gnw, gnb, A, oidx, odist, pe_buf, out);
    layer_kernel<false, false><<<dim3(N_PTS / 4), dim3(256), 0, stream>>>(1, W1, W2, b2, gnw, gnb, A, oidx, odist, pe_buf, out);
    layer_kernel<false, true ><<<dim3(N_PTS / 4), dim3(256), 0, stream>>>(2, W1, W2, b2, gnw, gnb, A, oidx, odist, pe_buf, out);
}

// Round 5
// 339.793 us; speedup vs baseline: 2.0760x; 1.1741x over previous
//
#include <hip/hip_runtime.h>

#define N_PTS   20000
#define M_ATOMS 10000
#define DAT     64
#define HID     129
#define KNN     16
#define NLAYERS 3

#define TILE_ATOMS 1024
#define NTILES     10         // 10*1024 = 10240 >= 10000
#define M_PAD      10240
#define A_HSTRIDE  132        // A row stride in HALVES (264 B, 8B-aligned)
#define PTS_PER_WAVE  2
#define PTS_PER_BLOCK 8       // 4 waves * 2

typedef _Float16 half2_t __attribute__((ext_vector_type(2)));

__device__ __forceinline__ float readlane_f(float v, int l) {
    return __int_as_float(__builtin_amdgcn_readlane(__float_as_int(v), l));
}

// ---------------- pack y -> float4(x,y,z,|y|^2), INF-padded ----------------
__global__ void pack_y_kernel(const float* __restrict__ y, float4* __restrict__ yp) {
    int i = blockIdx.x * blockDim.x + threadIdx.x;
    if (i >= M_PAD) return;
    if (i < M_ATOMS) {
        float a = y[3*i], b = y[3*i+1], c = y[3*i+2];
        float s = (a*a + b*b) + c*c;          // same order as (y**2).sum(1)
        yp[i] = make_float4(a, b, c, s);
    } else {
        yp[i] = make_float4(0.f, 0.f, 0.f, __builtin_inff());  // pad -> d2=INF
    }
}

// ---------------- brute-force exact kNN (K=16) ----------------
// 2 points/wave -> 10000 waves. Top-16 distributed in lanes 0..15, sorted
// ascending. First batch filled via bitonic sort (tie-break by index ==
// sequential-insert semantics). Steady-state insert: readlane extraction
// (no bpermute on chain head), unconditional ballot-suffix insert.
__global__ __launch_bounds__(256) void knn_kernel(
        const float* __restrict__ x, const float4* __restrict__ yp,
        int* __restrict__ oidx, float* __restrict__ odist) {
    __shared__ float4 tile[TILE_ATOMS];     // 16 KiB -> 8 blocks/CU
    const int tid  = threadIdx.x;
    const int lane = tid & 63;
    const int wid  = tid >> 6;
    const int base_pt = blockIdx.x * PTS_PER_BLOCK + wid * PTS_PER_WAVE;
    const float INF = __builtin_inff();

    float rx0 = 0.f, rx1 = 0.f, rx2 = 0.f, rx3 = 0.f;
    if (lane < PTS_PER_WAVE) {
        int pt = base_pt + lane;
        if (pt < N_PTS) {
            rx0 = x[3*pt]; rx1 = x[3*pt+1]; rx2 = x[3*pt+2];
            rx3 = (rx0*rx0 + rx1*rx1) + rx2*rx2;   // (x**2).sum(1) order
        }
    }
    float px[PTS_PER_WAVE], py[PTS_PER_WAVE], pz[PTS_PER_WAVE], ps[PTS_PER_WAVE];
#pragma unroll
    for (int p = 0; p < PTS_PER_WAVE; ++p) {
        px[p] = readlane_f(rx0, p); py[p] = readlane_f(rx1, p);
        pz[p] = readlane_f(rx2, p); ps[p] = readlane_f(rx3, p);
    }

    float Ld[PTS_PER_WAVE];  int Li[PTS_PER_WAVE];  float kth[PTS_PER_WAVE];

    // ---- tile 0 load ----
    for (int j = tid; j < TILE_ATOMS; j += 256) tile[j] = yp[j];
    __syncthreads();

    // ---- first batch (atoms 0..63): bitonic-sort fill of the top-16 list ----
    {
        float4 a = tile[lane];
#pragma unroll
        for (int p = 0; p < PTS_PER_WAVE; ++p) {
            float dot = (px[p] * a.x + py[p] * a.y) + pz[p] * a.z;
            float v   = (ps[p] - 2.f * dot) + a.w;   // same algebra as reference
            int   ix  = lane;                        // global atom index (t=0,it=0)
            // bitonic ascending sort across 64 lanes by (v, ix)
#pragma unroll
            for (int k = 2; k <= 64; k <<= 1) {
#pragma unroll
                for (int j2 = k >> 1; j2 > 0; j2 >>= 1) {
                    float ov = __shfl_xor(v, j2);
                    int   oi = __shfl_xor(ix, j2);
                    bool keepmin = (((lane & k) == 0) == ((lane & j2) == 0));
                    bool oless   = (ov < v) || (ov == v && oi < ix);
                    bool take    = (keepmin == oless);   // keepmin? oless : !oless
                    v  = take ? ov : v;
                    ix = take ? oi : ix;
                }
            }
            Ld[p]  = (lane < KNN) ? v : INF;
            Li[p]  = ix;
            kth[p] = readlane_f(v, 15);
        }
    }

    for (int t = 0; t < NTILES; ++t) {
        if (t > 0) {
            __syncthreads();
            for (int j = tid; j < TILE_ATOMS; j += 256) tile[j] = yp[t * TILE_ATOMS + j];
            __syncthreads();
        }
        const int abase = t * TILE_ATOMS;
#pragma unroll 2
        for (int it = (t == 0 ? 1 : 0); it < TILE_ATOMS / 64; ++it) {
            float4 a = tile[it * 64 + lane];        // read ONCE, serve both points
            const int cbase = abase + it * 64;
#pragma unroll
            for (int p = 0; p < PTS_PER_WAVE; ++p) {
                // selection metric in the SAME algebra as reference: (x2 - 2*dot) + y2
                float dot = (px[p] * a.x + py[p] * a.y) + pz[p] * a.z;
                float d2  = (ps[p] - 2.f * dot) + a.w;
                unsigned long long cand = __ballot(d2 < kth[p]);
                if (cand) {
                    do {                                  // uniform loop
                        int src = __builtin_ctzll(cand);  // ascending atom index
                        cand &= cand - 1;
                        float v  = readlane_f(d2, src);   // SGPR broadcast, no LDS op
                        int   mi = cbase + src;
                        // suffix of lanes whose Ld > v (strict: stable ties, lower idx first).
                        // If v >= Ld[15], bits 0..15 are clear -> no-op on the list (safe).
                        unsigned long long bal  = __ballot(Ld[p] > v);
                        float pd = __shfl_up(Ld[p], 1);
                        int   pi = __shfl_up(Li[p], 1);
                        unsigned long long balp = bal << 1;
                        bool sel  = (bal  >> lane) & 1ull;
                        bool selp = (balp >> lane) & 1ull;
                        Ld[p] = sel ? (selp ? pd : v)  : Ld[p];
                        Li[p] = sel ? (selp ? pi : mi) : Li[p];
                    } while (cand);
                    kth[p] = readlane_f(Ld[p], 15);       // once per batch
                }
            }
        }
    }

#pragma unroll
    for (int p = 0; p < PTS_PER_WAVE; ++p) {
        int pt = base_pt + p;
        if (pt >= N_PTS) continue;
        int ii = Li[p];
        float4 a = yp[ii];
        float dx = px[p] - a.x, dy = py[p] - a.y, dz = pz[p] - a.z;
        float dist = (dx*dx + dy*dy) + dz*dz;      // ((x-y)**2).sum(-1) order
        if (lane < KNN) {
            oidx [pt * KNN + lane] = ii;
            odist[pt * KNN + lane] = dist;
        }
    }
}

// ---------------- per-atom precompute: A[l][i] = feats[i] @ W1[l][64:128] + b1[l] (fp16) ----------------
// Channel remap: lane owns HID channels (2*lane, 2*lane+1); channel 128 separate.
#define ATOMS_PER_WAVE 8
#define A_GROUPS (M_ATOMS / ATOMS_PER_WAVE)        // 1250
__global__ __launch_bounds__(256) void precompute_A_kernel(
        const float* __restrict__ feats, const float* __restrict__ W1,
        const float* __restrict__ b1, _Float16* __restrict__ A) {
    int wid = threadIdx.x >> 6, lane = threadIdx.x & 63;
    int id = blockIdx.x * 4 + wid;
    if (id >= NLAYERS * A_GROUPS) return;
    int l = id / A_GROUPS, g = id - l * A_GROUPS;
    int base_atom = g * ATOMS_PER_WAVE;

    float f[ATOMS_PER_WAVE];
#pragma unroll
    for (int a = 0; a < ATOMS_PER_WAVE; ++a) f[a] = feats[(base_atom + a) * DAT + lane];

    float a0[ATOMS_PER_WAVE], a1[ATOMS_PER_WAVE], a2[ATOMS_PER_WAVE];
#pragma unroll
    for (int a = 0; a < ATOMS_PER_WAVE; ++a) { a0[a] = 0.f; a1[a] = 0.f; a2[a] = 0.f; }

    const float* Wl = W1 + (size_t)l * HID * HID;
#pragma unroll 4
    for (int d = 0; d < DAT; ++d) {
        const float* row = Wl + (64 + d) * HID;    // feats rows of W1
        float w0 = row[2 * lane];
        float w1 = row[2 * lane + 1];
        float w2 = row[128];
#pragma unroll
        for (int a = 0; a < ATOMS_PER_WAVE; ++a) {
            float s = readlane_f(f[a], d);         // uniform broadcast, no LDS op
            a0[a] += s * w0;
            a1[a] += s * w1;
            a2[a] += s * w2;
        }
    }
    const float* b1l = b1 + l * HID;
    float bb0 = b1l[2 * lane], bb1 = b1l[2 * lane + 1], bb2 = b1l[128];
#pragma unroll
    for (int a = 0; a < ATOMS_PER_WAVE; ++a) {
        _Float16* Ar = A + ((size_t)l * M_ATOMS + base_atom + a) * A_HSTRIDE;
        half2_t hv; hv.x = (_Float16)(a0[a] + bb0); hv.y = (_Float16)(a1[a] + bb1);
        ((half2_t*)Ar)[lane] = hv;
        if (lane == 0) Ar[128] = (_Float16)(a2[a] + bb2);
    }
}

// ---------------- one layer of the MLP + groupnorm, one wave per point ----------------
// Per-layer launch => exactly one 2.64 MB A-slice hot in L2 at a time.
template<bool FIRST, bool LAST>
__global__ __launch_bounds__(256) void layer_kernel(
        int l,
        const float* __restrict__ W1, const float* __restrict__ W2,
        const float* __restrict__ b2, const float* __restrict__ gnw,
        const float* __restrict__ gnb, const _Float16* __restrict__ A,
        const int* __restrict__ oidx, const float* __restrict__ odist,
        float* __restrict__ pe_buf, float* __restrict__ out) {
    int wid = threadIdx.x >> 6, lane = threadIdx.x & 63;
    int n = blockIdx.x * 4 + wid;                  // 5000*4 == 20000 exact

    float pe = FIRST ? 1.0f : pe_buf[n * DAT + lane];
    int   ikl = 0; float dkl = 0.f;
    if (lane < KNN) { ikl = oidx[n * KNN + lane]; dkl = odist[n * KNN + lane]; }
    int ii[KNN]; float dd[KNN];
#pragma unroll
    for (int k = 0; k < KNN; ++k) {
        ii[k] = __builtin_amdgcn_readlane(ikl, k);
        dd[k] = readlane_f(dkl, k);
    }

    // prefetch gathered fp16 A rows (one coalesced 256B load + one scalar each);
    // latency covered by the 64-iteration p-matmul below.
    half2_t Av01[KNN]; _Float16 Av2[KNN];
#pragma unroll
    for (int k = 0; k < KNN; ++k) {
        const _Float16* Ar = A + ((size_t)l * M_ATOMS + ii[k]) * A_HSTRIDE;
        Av01[k] = ((const half2_t*)Ar)[lane];
        Av2[k]  = Ar[128];
    }

    const float* Wl = W1 + (size_t)l * HID * HID;
    // p = pe @ W1[l][0:64]; lane owns HID channels (2*lane, 2*lane+1), plus 128
    float p0 = 0.f, p1 = 0.f, p2 = 0.f;
#pragma unroll 8
    for (int d = 0; d < DAT; ++d) {
        float s = readlane_f(pe, d);               // VALU broadcast, no LDS op
        const float* row = Wl + d * HID;
        p0 += s * row[2 * lane];
        p1 += s * row[2 * lane + 1];
        p2 += s * row[128];
    }
    const float* wl = Wl + 128 * HID;              // dist row of W1
    float wl0 = wl[2 * lane], wl1 = wl[2 * lane + 1], wl2 = wl[128];

    // hsum = sum_k leaky(p + A[idx_k] + dist_k * wl)
    float hs0 = 0.f, hs1 = 0.f, hs2 = 0.f;
#pragma unroll
    for (int k = 0; k < KNN; ++k) {
        float A0 = (float)Av01[k].x, A1 = (float)Av01[k].y, A2 = (float)Av2[k];
        float h0 = p0 + A0 + dd[k] * wl0; h0 = h0 >= 0.f ? h0 : 0.2f * h0; hs0 += h0;
        float h1 = p1 + A1 + dd[k] * wl1; h1 = h1 >= 0.f ? h1 : 0.2f * h1; hs1 += h1;
        float h2 = p2 + A2 + dd[k] * wl2; h2 = h2 >= 0.f ? h2 : 0.2f * h2; hs2 += h2;
    }

    // msg = hsum @ W2[l] + K*b2[l]  (sum over k hoisted before the matmul)
    const float* W2l = W2 + (size_t)l * HID * DAT;
    float m = 0.f;
#pragma unroll 8
    for (int j = 0; j < DAT; ++j) {
        float a0 = readlane_f(hs0, j), a1 = readlane_f(hs1, j);
        m += a0 * W2l[(2 * j) * DAT + lane];
        m += a1 * W2l[(2 * j + 1) * DAT + lane];
    }
    m += hs2 * W2l[128 * DAT + lane];
    m += 16.f * b2[l * DAT + lane];

    // GroupNorm(2 groups of 32 channels) — reduce within aligned 32-lane halves
    float s1 = m;
    s1 += __shfl_xor(s1, 1);  s1 += __shfl_xor(s1, 2);  s1 += __shfl_xor(s1, 4);
    s1 += __shfl_xor(s1, 8);  s1 += __shfl_xor(s1, 16);
    float mu = s1 * (1.f / 32.f);
    float dm = m - mu;
    float s2 = dm * dm;
    s2 += __shfl_xor(s2, 1);  s2 += __shfl_xor(s2, 2);  s2 += __shfl_xor(s2, 4);
    s2 += __shfl_xor(s2, 8);  s2 += __shfl_xor(s2, 16);
    float var = s2 * (1.f / 32.f);
    float g = dm * (1.f / sqrtf(var + 1e-5f)) * gnw[l * DAT + lane] + gnb[l * DAT + lane];
    pe += (g >= 0.f) ? g : 0.2f * g;               // leaky, residual add

    if (LAST) out[n * DAT + lane] = pe;
    else      pe_buf[n * DAT + lane] = pe;
}

// ---------------- launch ----------------
extern "C" void kernel_launch(void* const* d_in, const int* in_sizes, int n_in,
                              void* d_out, int out_size, void* d_ws, size_t ws_size,
                              hipStream_t stream) {
    const float* x     = (const float*)d_in[0];
    const float* y     = (const float*)d_in[1];
    const float* feats = (const float*)d_in[2];
    const float* W1    = (const float*)d_in[3];
    const float* b1    = (const float*)d_in[4];
    const float* W2    = (const float*)d_in[5];
    const float* b2    = (const float*)d_in[6];
    const float* gnw   = (const float*)d_in[7];
    const float* gnb   = (const float*)d_in[8];
    float* out = (float*)d_out;

    char* ws = (char*)d_ws;
    float4*    yp    = (float4*)ws;                       // 10240*16        = 163,840 B
    int*       oidx  = (int*)   (ws + 163840);            // 20000*16*4      = 1,280,000 B
    float*     odist = (float*) (ws + 163840 + 1280000);  // 1,280,000 B
    _Float16*  A     = (_Float16*)(ws + 2723840);         // 3*10000*132*2   = 7,920,000 B
    float*     pe_buf= (float*) (ws + 2723840 + 7920000); // 20000*64*4      = 5,120,000 B
    // total ~15.8 MB of ws

    pack_y_kernel<<<dim3((M_PAD + 255) / 256), dim3(256), 0, stream>>>(y, yp);
    knn_kernel<<<dim3(N_PTS / PTS_PER_BLOCK), dim3(256), 0, stream>>>(x, yp, oidx, odist);
    precompute_A_kernel<<<dim3((NLAYERS * A_GROUPS + 3) / 4), dim3(256), 0, stream>>>(feats, W1, b1, A);
    layer_kernel<true,  false><<<dim3(N_PTS / 4), dim3(256), 0, stream>>>(0, W1, W2, b2, gnw, gnb, A, oidx, odist, pe_buf, out);
    layer_kernel<false, false><<<dim3(N_PTS / 4), dim3(256), 0, stream>>>(1, W1, W2, b2, gnw, gnb, A, oidx, odist, pe_buf, out);
    layer_kernel<false, true ><<<dim3(N_PTS / 4), dim3(256), 0, stream>>>(2, W1, W2, b2, gnw, gnb, A, oidx, odist, pe_buf, out);
}

// Round 6
// 259.401 us; speedup vs baseline: 2.7194x; 1.3099x over previous
//
#include <hip/hip_runtime.h>

#define N_PTS   20000
#define M_ATOMS 10000
#define DAT     64
#define HID     129
#define KNN     16
#define NLAYERS 3

#define TILE_ATOMS 1024
#define NTILES     10         // 10*1024 = 10240 >= 10000
#define A_HSTRIDE  132        // A row stride in HALVES (264 B, 8B-aligned)
#define KNN_BLOCKS 2048       // 8192 waves == 32 waves/CU exactly
#define PTS_L      2          // points per wave in layer kernel

typedef _Float16 half2_t __attribute__((ext_vector_type(2)));

__device__ __forceinline__ float readlane_f(float v, int l) {
    return __int_as_float(__builtin_amdgcn_readlane(__float_as_int(v), l));
}

// ---------------- brute-force exact kNN (K=16) ----------------
// 8192 waves, each owns 2-3 points (balanced, single occupancy round).
// Top-16 distributed in lanes 0..15 sorted ascending (whole 64-lane array
// stays globally sorted; lanes 16+ hold spillover). Insert position from
// SALU ctz(ballot); per-lane predicate used directly.
__global__ __launch_bounds__(256) void knn_kernel(
        const float* __restrict__ x, const float* __restrict__ y,
        int* __restrict__ oidx, float* __restrict__ odist) {
    __shared__ float4 tile[TILE_ATOMS];     // 16 KiB -> 8 blocks/CU
    const int tid  = threadIdx.x;
    const int lane = tid & 63;
    const int wid  = tid >> 6;
    const int w    = blockIdx.x * 4 + wid;          // 0..8191
    const int start = (w * 625) >> 8;               // w*20000/8192
    const int npts  = (((w + 1) * 625) >> 8) - start;   // 2 or 3
    const float INF = __builtin_inff();

    float rx0 = 0.f, rx1 = 0.f, rx2 = 0.f, rx3 = 0.f;
    if (lane < npts) {
        int pt = start + lane;
        rx0 = x[3*pt]; rx1 = x[3*pt+1]; rx2 = x[3*pt+2];
        rx3 = (rx0*rx0 + rx1*rx1) + rx2*rx2;        // (x**2).sum(1) order
    }
    float px[3], py[3], pz[3], ps[3];
#pragma unroll
    for (int p = 0; p < 3; ++p) {
        px[p] = readlane_f(rx0, p); py[p] = readlane_f(rx1, p);
        pz[p] = readlane_f(rx2, p); ps[p] = readlane_f(rx3, p);
    }

    float Ld[3];  int Li[3];  float kth[3];

    // ---- tile 0 load (pack y + |y|^2 on the fly; pads -> INF) ----
    for (int j = tid; j < TILE_ATOMS; j += 256) {
        float4 v4;
        if (j < M_ATOMS) {
            float a = y[3*j], b = y[3*j+1], c = y[3*j+2];
            v4 = make_float4(a, b, c, (a*a + b*b) + c*c);   // (y**2).sum(1) order
        } else v4 = make_float4(0.f, 0.f, 0.f, INF);
        tile[j] = v4;
    }
    __syncthreads();

    // ---- first batch (atoms 0..63): bitonic-sort fill of the top-16 list ----
    {
        float4 a = tile[lane];
#pragma unroll
        for (int p = 0; p < 3; ++p) {
            if (p == 2 && npts < 3) continue;       // uniform guard
            float dot = (px[p] * a.x + py[p] * a.y) + pz[p] * a.z;
            float v   = (ps[p] - 2.f * dot) + a.w;  // same algebra as reference
            int   ix  = lane;
#pragma unroll
            for (int k = 2; k <= 64; k <<= 1) {
#pragma unroll
                for (int j2 = k >> 1; j2 > 0; j2 >>= 1) {
                    float ov = __shfl_xor(v, j2);
                    int   oi = __shfl_xor(ix, j2);
                    bool keepmin = (((lane & k) == 0) == ((lane & j2) == 0));
                    bool oless   = (ov < v) || (ov == v && oi < ix);
                    bool take    = (keepmin == oless);
                    v  = take ? ov : v;
                    ix = take ? oi : ix;
                }
            }
            Ld[p]  = (lane < KNN) ? v : INF;
            Li[p]  = ix;
            kth[p] = readlane_f(v, 15);
        }
    }

    for (int t = 0; t < NTILES; ++t) {
        if (t > 0) {
            __syncthreads();
            for (int j = tid; j < TILE_ATOMS; j += 256) {
                int g = t * TILE_ATOMS + j;
                float4 v4;
                if (g < M_ATOMS) {
                    float a = y[3*g], b = y[3*g+1], c = y[3*g+2];
                    v4 = make_float4(a, b, c, (a*a + b*b) + c*c);
                } else v4 = make_float4(0.f, 0.f, 0.f, INF);
                tile[j] = v4;
            }
            __syncthreads();
        }
        const int abase = t * TILE_ATOMS;
#pragma unroll 2
        for (int it = (t == 0 ? 1 : 0); it < TILE_ATOMS / 64; ++it) {
            float4 a = tile[it * 64 + lane];        // read ONCE, serve all points
            const int cbase = abase + it * 64;
#pragma unroll
            for (int p = 0; p < 3; ++p) {
                if (p == 2 && npts < 3) continue;   // uniform guard
                // selection metric in the SAME algebra as reference: (x2 - 2*dot) + y2
                float dot = (px[p] * a.x + py[p] * a.y) + pz[p] * a.z;
                float d2  = (ps[p] - 2.f * dot) + a.w;
                unsigned long long cand = __ballot(d2 < kth[p]);
                if (cand) {
                    do {                                  // uniform loop
                        int src = __builtin_ctzll(cand);  // ascending atom index
                        cand &= cand - 1;
                        float v  = readlane_f(d2, src);   // SGPR broadcast
                        int   mi = cbase + src;           // SGPR (uniform)
                        bool pred = Ld[p] > v;            // strict: stable ties
                        unsigned long long bal = __ballot(pred);
                        int ins = __builtin_ctzll(bal);   // SALU insert position
                        float pd = __shfl_up(Ld[p], 1);
                        int   pi = __shfl_up(Li[p], 1);
                        bool atins = (lane == ins);
                        float tv = atins ? v  : pd;
                        int   ti = atins ? mi : pi;
                        Ld[p] = pred ? tv : Ld[p];
                        Li[p] = pred ? ti : Li[p];
                    } while (cand);
                    kth[p] = readlane_f(Ld[p], 15);       // once per batch
                }
            }
        }
    }

#pragma unroll
    for (int p = 0; p < 3; ++p) {
        if (p == 2 && npts < 3) continue;
        int pt = start + p;
        int ii = Li[p];                            // real atom idx (<10000) in all lanes
        float ax = y[3*ii], ay = y[3*ii+1], az = y[3*ii+2];
        float dx = px[p] - ax, dy = py[p] - ay, dz = pz[p] - az;
        float dist = (dx*dx + dy*dy) + dz*dz;      // ((x-y)**2).sum(-1) order
        if (lane < KNN) {
            oidx [pt * KNN + lane] = ii;
            odist[pt * KNN + lane] = dist;
        }
    }
}

// ---------------- per-atom precompute: A[l][i] = feats[i] @ W1[l][64:128] + b1[l] (fp16) ----------------
// Channel remap: lane owns HID channels (2*lane, 2*lane+1); channel 128 separate.
#define ATOMS_PER_WAVE 8
#define A_GROUPS (M_ATOMS / ATOMS_PER_WAVE)        // 1250
__global__ __launch_bounds__(256) void precompute_A_kernel(
        const float* __restrict__ feats, const float* __restrict__ W1,
        const float* __restrict__ b1, _Float16* __restrict__ A) {
    int wid = threadIdx.x >> 6, lane = threadIdx.x & 63;
    int id = blockIdx.x * 4 + wid;
    if (id >= NLAYERS * A_GROUPS) return;
    int l = id / A_GROUPS, g = id - l * A_GROUPS;
    int base_atom = g * ATOMS_PER_WAVE;

    float f[ATOMS_PER_WAVE];
#pragma unroll
    for (int a = 0; a < ATOMS_PER_WAVE; ++a) f[a] = feats[(base_atom + a) * DAT + lane];

    float a0[ATOMS_PER_WAVE], a1[ATOMS_PER_WAVE], a2[ATOMS_PER_WAVE];
#pragma unroll
    for (int a = 0; a < ATOMS_PER_WAVE; ++a) { a0[a] = 0.f; a1[a] = 0.f; a2[a] = 0.f; }

    const float* Wl = W1 + (size_t)l * HID * HID;
#pragma unroll 4
    for (int d = 0; d < DAT; ++d) {
        const float* row = Wl + (64 + d) * HID;
        float w0 = row[2 * lane];
        float w1 = row[2 * lane + 1];
        float w2 = row[128];
#pragma unroll
        for (int a = 0; a < ATOMS_PER_WAVE; ++a) {
            float s = readlane_f(f[a], d);
            a0[a] += s * w0;
            a1[a] += s * w1;
            a2[a] += s * w2;
        }
    }
    const float* b1l = b1 + l * HID;
    float bb0 = b1l[2 * lane], bb1 = b1l[2 * lane + 1], bb2 = b1l[128];
#pragma unroll
    for (int a = 0; a < ATOMS_PER_WAVE; ++a) {
        _Float16* Ar = A + ((size_t)l * M_ATOMS + base_atom + a) * A_HSTRIDE;
        half2_t hv; hv.x = (_Float16)(a0[a] + bb0); hv.y = (_Float16)(a1[a] + bb1);
        ((half2_t*)Ar)[lane] = hv;
        if (lane == 0) Ar[128] = (_Float16)(a2[a] + bb2);
    }
}

// ---------------- one layer of the MLP + groupnorm ----------------
// W1/W2 staged in LDS (64 KB) once per 512-thread block; each of 8 waves
// handles PTS_L points. Weight L2 traffic: 68KB/point -> 64KB/block.
template<bool FIRST, bool LAST>
__global__ __launch_bounds__(512) void layer_kernel(
        int l,
        const float* __restrict__ W1, const float* __restrict__ W2,
        const float* __restrict__ b2, const float* __restrict__ gnw,
        const float* __restrict__ gnb, const _Float16* __restrict__ A,
        const int* __restrict__ oidx, const float* __restrict__ odist,
        float* __restrict__ pe_buf, float* __restrict__ out) {
    __shared__ float2 w1s[64 * 64];   // [d][lane] = (W1[d][2l], W1[d][2l+1])   32KB
    __shared__ float2 w2s[64 * 64];   // [j][lane] = (W2[2j][l..], W2[2j+1][..]) 32KB
    const int wave = threadIdx.x >> 6, lane = threadIdx.x & 63;

    const float* Wl  = W1 + (size_t)l * HID * HID;
    const float* W2l = W2 + (size_t)l * HID * DAT;
    for (int d = wave; d < 64; d += 8) {
        w1s[d * 64 + lane] = make_float2(Wl[d * HID + 2 * lane], Wl[d * HID + 2 * lane + 1]);
        w2s[d * 64 + lane] = make_float2(W2l[(2 * d) * DAT + lane], W2l[(2 * d + 1) * DAT + lane]);
    }
    // per-lane constants (registers)
    const float wl0 = Wl[128 * HID + 2 * lane], wl1 = Wl[128 * HID + 2 * lane + 1];
    const float wl2 = Wl[128 * HID + 128];
    const float w1c = Wl[lane * HID + 128];        // col-128 of W1 rows 0..63
    const float w2c = W2l[128 * DAT + lane];
    const float b2v = 16.f * b2[l * DAT + lane];
    const float gw  = gnw[l * DAT + lane], gb = gnb[l * DAT + lane];
    __syncthreads();

    // layer 0: pe == 1 for every point -> p-vector is point-independent
    float fp0 = 0.f, fp1 = 0.f, fp2 = 0.f;
    if (FIRST) {
#pragma unroll 8
        for (int d = 0; d < 64; ++d) {
            float2 w2v = w1s[d * 64 + lane];
            fp0 += w2v.x; fp1 += w2v.y;
        }
        float v = w1c;
        v += __shfl_xor(v, 1);  v += __shfl_xor(v, 2);  v += __shfl_xor(v, 4);
        v += __shfl_xor(v, 8);  v += __shfl_xor(v, 16); v += __shfl_xor(v, 32);
        fp2 = v;
    }

    const _Float16* Al = A + (size_t)l * M_ATOMS * A_HSTRIDE;

#pragma unroll
    for (int pt = 0; pt < PTS_L; ++pt) {
        const int n = (blockIdx.x * 8 + wave) * PTS_L + pt;   // 1250*8*2 == 20000

        float pe = FIRST ? 1.0f : pe_buf[n * DAT + lane];
        int   ikl = 0; float dkl = 0.f;
        if (lane < KNN) { ikl = oidx[n * KNN + lane]; dkl = odist[n * KNN + lane]; }
        int ii[KNN]; float dd[KNN];
#pragma unroll
        for (int k = 0; k < KNN; ++k) {
            ii[k] = __builtin_amdgcn_readlane(ikl, k);
            dd[k] = readlane_f(dkl, k);
        }

        // prefetch gathered fp16 A rows (coalesced 256B + scalar each)
        half2_t Av01[KNN]; _Float16 Av2[KNN];
#pragma unroll
        for (int k = 0; k < KNN; ++k) {
            const _Float16* Ar = Al + (size_t)ii[k] * A_HSTRIDE;
            Av01[k] = ((const half2_t*)Ar)[lane];
            Av2[k]  = Ar[128];
        }

        float p0, p1, p2;
        if (FIRST) { p0 = fp0; p1 = fp1; p2 = fp2; }
        else {
            p0 = 0.f; p1 = 0.f;
#pragma unroll 8
            for (int d = 0; d < 64; ++d) {
                float s = readlane_f(pe, d);
                float2 w2v = w1s[d * 64 + lane];
                p0 += s * w2v.x;
                p1 += s * w2v.y;
            }
            float v = pe * w1c;                    // dot(pe, W1[:,128]) via reduce
            v += __shfl_xor(v, 1);  v += __shfl_xor(v, 2);  v += __shfl_xor(v, 4);
            v += __shfl_xor(v, 8);  v += __shfl_xor(v, 16); v += __shfl_xor(v, 32);
            p2 = v;
        }

        // hsum = sum_k leaky(p + A[idx_k] + dist_k * wl)
        float hs0 = 0.f, hs1 = 0.f, hs2 = 0.f;
#pragma unroll
        for (int k = 0; k < KNN; ++k) {
            float A0 = (float)Av01[k].x, A1 = (float)Av01[k].y, A2 = (float)Av2[k];
            float h0 = p0 + A0 + dd[k] * wl0; h0 = h0 >= 0.f ? h0 : 0.2f * h0; hs0 += h0;
            float h1 = p1 + A1 + dd[k] * wl1; h1 = h1 >= 0.f ? h1 : 0.2f * h1; hs1 += h1;
            float h2 = p2 + A2 + dd[k] * wl2; h2 = h2 >= 0.f ? h2 : 0.2f * h2; hs2 += h2;
        }

        // msg = hsum @ W2[l] + K*b2[l]
        float m0 = 0.f, m1 = 0.f;
#pragma unroll 8
        for (int j = 0; j < 64; j += 2) {
            float a0 = readlane_f(hs0, j),     a1 = readlane_f(hs1, j);
            float b0 = readlane_f(hs0, j + 1), b1 = readlane_f(hs1, j + 1);
            float2 wa = w2s[j * 64 + lane];
            float2 wb = w2s[(j + 1) * 64 + lane];
            m0 += a0 * wa.x; m0 += a1 * wa.y;
            m1 += b0 * wb.x; m1 += b1 * wb.y;
        }
        float m = (m0 + m1) + hs2 * w2c + b2v;

        // GroupNorm(2 groups of 32 channels) within aligned 32-lane halves
        float s1 = m;
        s1 += __shfl_xor(s1, 1);  s1 += __shfl_xor(s1, 2);  s1 += __shfl_xor(s1, 4);
        s1 += __shfl_xor(s1, 8);  s1 += __shfl_xor(s1, 16);
        float mu = s1 * (1.f / 32.f);
        float dm = m - mu;
        float s2 = dm * dm;
        s2 += __shfl_xor(s2, 1);  s2 += __shfl_xor(s2, 2);  s2 += __shfl_xor(s2, 4);
        s2 += __shfl_xor(s2, 8);  s2 += __shfl_xor(s2, 16);
        float var = s2 * (1.f / 32.f);
        float g = dm * (1.f / sqrtf(var + 1e-5f)) * gw + gb;
        pe += (g >= 0.f) ? g : 0.2f * g;           // leaky, residual add

        if (LAST) out[n * DAT + lane] = pe;
        else      pe_buf[n * DAT + lane] = pe;
    }
}

// ---------------- launch ----------------
extern "C" void kernel_launch(void* const* d_in, const int* in_sizes, int n_in,
                              void* d_out, int out_size, void* d_ws, size_t ws_size,
                              hipStream_t stream) {
    const float* x     = (const float*)d_in[0];
    const float* y     = (const float*)d_in[1];
    const float* feats = (const float*)d_in[2];
    const float* W1    = (const float*)d_in[3];
    const float* b1    = (const float*)d_in[4];
    const float* W2    = (const float*)d_in[5];
    const float* b2    = (const float*)d_in[6];
    const float* gnw   = (const float*)d_in[7];
    const float* gnb   = (const float*)d_in[8];
    float* out = (float*)d_out;

    char* ws = (char*)d_ws;
    int*       oidx  = (int*)    ws;                        // 20000*16*4 = 1,280,000 B
    float*     odist = (float*) (ws + 1280000);             // 1,280,000 B
    _Float16*  A     = (_Float16*)(ws + 2560000);           // 3*10000*132*2 = 7,920,000 B
    float*     pe_buf= (float*) (ws + 2560000 + 7920000);   // 20000*64*4 = 5,120,000 B
    // total ~15.7 MB of ws

    knn_kernel<<<dim3(KNN_BLOCKS), dim3(256), 0, stream>>>(x, y, oidx, odist);
    precompute_A_kernel<<<dim3((NLAYERS * A_GROUPS + 3) / 4), dim3(256), 0, stream>>>(feats, W1, b1, A);
    layer_kernel<true,  false><<<dim3(1250), dim3(512), 0, stream>>>(0, W1, W2, b2, gnw, gnb, A, oidx, odist, pe_buf, out);
    layer_kernel<false, false><<<dim3(1250), dim3(512), 0, stream>>>(1, W1, W2, b2, gnw, gnb, A, oidx, odist, pe_buf, out);
    layer_kernel<false, true ><<<dim3(1250), dim3(512), 0, stream>>>(2, W1, W2, b2, gnw, gnb, A, oidx, odist, pe_buf, out);
}